// Round 1
// baseline (1934.864 us; speedup 1.0000x reference)
//
#include <hip/hip_runtime.h>

#define N_TOK 16384
#define HID   4096
#define N_EXP 64
#define TOPK  8

// d_out layout (floats, concatenated in reference return order)
#define OFF_ROUTER 0
#define OFF_WT   (N_TOK * N_EXP)                  // 1048576
#define OFF_IDX  (OFF_WT + N_TOK * TOPK)          // 1179648
#define OFF_MASK (OFF_IDX + N_TOK * TOPK)         // 1310720
#define MASK_ELEMS (N_EXP * TOPK * N_TOK)         // 8388608

// ---------------------------------------------------------------------------
// Kernel A: router logits = x @ W^T + b
// grid 256 blocks x 256 threads. Block b: tokens [b*64, b*64+64).
// Wave w (of 4): experts [w*16, w*16+16). Thread lane = token.
// W is read via wave-uniform addresses -> scalar loads (SGPR broadcast):
// no per-lane LDS/L1 traffic for W. Only x goes through LDS (transpose).
// ---------------------------------------------------------------------------
__global__ __launch_bounds__(256, 1)
void router_gemm(const float* __restrict__ x, const float* __restrict__ W,
                 const float* __restrict__ b, float* __restrict__ router)
{
    __shared__ float xs[2][64][65];   // stride 65: conflict-free b32 reads

    const int tid  = threadIdx.x;
    const int lane = tid & 63;
    const int wv   = __builtin_amdgcn_readfirstlane(tid >> 6); // force SGPR
    const int t0   = blockIdx.x * 64;
    const int ew0  = wv * 16;

    float acc[16];
#pragma unroll
    for (int e = 0; e < 16; ++e) acc[e] = 0.f;

    const float* xbase = x + (long)t0 * HID;

    // stage chunk 0: thread handles float4 id f4 = tid + 256k; 16 float4/row
    float4 pf[4];
#pragma unroll
    for (int k = 0; k < 4; ++k) {
        int f4 = tid + 256 * k;
        int row = f4 >> 4, c4 = f4 & 15;
        pf[k] = *(const float4*)(xbase + (long)row * HID + c4 * 4);
    }
#pragma unroll
    for (int k = 0; k < 4; ++k) {
        int f4 = tid + 256 * k;
        int row = f4 >> 4, c4 = f4 & 15;
        xs[0][row][c4 * 4 + 0] = pf[k].x;
        xs[0][row][c4 * 4 + 1] = pf[k].y;
        xs[0][row][c4 * 4 + 2] = pf[k].z;
        xs[0][row][c4 * 4 + 3] = pf[k].w;
    }
    __syncthreads();

    for (int c = 0; c < HID / 64; ++c) {
        const int buf = c & 1;
        const int hb  = c * 64;

        if (c + 1 < HID / 64) {            // prefetch next chunk into regs
#pragma unroll
            for (int k = 0; k < 4; ++k) {
                int f4 = tid + 256 * k;
                int row = f4 >> 4, c4 = f4 & 15;
                pf[k] = *(const float4*)(xbase + (long)row * HID + (hb + 64) + c4 * 4);
            }
        }

        const float* Wc = W + (long)ew0 * HID + hb;   // wave-uniform base
#pragma unroll
        for (int h4 = 0; h4 < 16; ++h4) {
            float x0 = xs[buf][lane][h4 * 4 + 0];
            float x1 = xs[buf][lane][h4 * 4 + 1];
            float x2 = xs[buf][lane][h4 * 4 + 2];
            float x3 = xs[buf][lane][h4 * 4 + 3];
#pragma unroll
            for (int e = 0; e < 16; ++e) {
                const float* wr = Wc + (long)e * HID + h4 * 4;  // uniform -> s_load
                float a = acc[e];
                a = fmaf(wr[0], x0, a);
                a = fmaf(wr[1], x1, a);
                a = fmaf(wr[2], x2, a);
                a = fmaf(wr[3], x3, a);
                acc[e] = a;
            }
        }

        if (c + 1 < HID / 64) {            // write prefetched chunk to other buf
            const int nb = buf ^ 1;
#pragma unroll
            for (int k = 0; k < 4; ++k) {
                int f4 = tid + 256 * k;
                int row = f4 >> 4, c4 = f4 & 15;
                xs[nb][row][c4 * 4 + 0] = pf[k].x;
                xs[nb][row][c4 * 4 + 1] = pf[k].y;
                xs[nb][row][c4 * 4 + 2] = pf[k].z;
                xs[nb][row][c4 * 4 + 3] = pf[k].w;
            }
        }
        __syncthreads();
    }

    // epilogue: + bias, write 16 consecutive experts for my token
    float* out = router + (long)(t0 + lane) * N_EXP + ew0;
#pragma unroll
    for (int q = 0; q < 4; ++q) {
        float4 v;
        v.x = acc[q * 4 + 0] + b[ew0 + q * 4 + 0];
        v.y = acc[q * 4 + 1] + b[ew0 + q * 4 + 1];
        v.z = acc[q * 4 + 2] + b[ew0 + q * 4 + 2];
        v.w = acc[q * 4 + 3] + b[ew0 + q * 4 + 3];
        *(float4*)(out + q * 4) = v;
    }
}

// ---------------------------------------------------------------------------
// Kernel B: per-token softmax + top-8 (tie -> lowest index, matching
// jax.lax.top_k) + renormalized weights + scatter into one-hot mask.
// One wave per token; 4 tokens per 256-thread block.
// ---------------------------------------------------------------------------
__global__ __launch_bounds__(256, 1)
void router_topk(const float* __restrict__ router, float* __restrict__ out)
{
    const int tid  = threadIdx.x;
    const int lane = tid & 63;
    const int wv   = tid >> 6;
    const int n    = blockIdx.x * 4 + wv;

    float l = router[(long)n * N_EXP + lane];

    // softmax over 64 experts (one logit per lane)
    float m = l;
#pragma unroll
    for (int o = 32; o > 0; o >>= 1) m = fmaxf(m, __shfl_xor(m, o));
    float p = expf(l - m);
    float Z = p;
#pragma unroll
    for (int o = 32; o > 0; o >>= 1) Z += __shfl_xor(Z, o);
    float prob = p / Z;

    // iterative top-8 via butterfly argmax (lexicographic: max val, min idx)
    float cur = prob;
    float myv = 0.f;      // lane k (k<8) keeps the k-th winner
    int   myi = 0;
    float ssum = 0.f;     // uniform: sum of selected probs
#pragma unroll
    for (int k = 0; k < TOPK; ++k) {
        float v = cur;
        int   id = lane;
#pragma unroll
        for (int o = 32; o > 0; o >>= 1) {
            float ov = __shfl_xor(v, o);
            int   oi = __shfl_xor(id, o);
            if (ov > v || (ov == v && oi < id)) { v = ov; id = oi; }
        }
        // v,id are now uniform across the wave
        if (lane == k)  { myv = v; myi = id; }
        if (lane == id) cur = -1.f;        // exclude winner
        ssum += v;
    }

    if (lane < TOPK) {
        out[OFF_WT  + (long)n * TOPK + lane] = myv / ssum;
        out[OFF_IDX + (long)n * TOPK + lane] = (float)myi;
        // expert_mask[e][k][n] = 1
        out[OFF_MASK + (long)myi * (TOPK * N_TOK) + (long)lane * N_TOK + n] = 1.0f;
    }
}

extern "C" void kernel_launch(void* const* d_in, const int* in_sizes, int n_in,
                              void* d_out, int out_size, void* d_ws, size_t ws_size,
                              hipStream_t stream)
{
    const float* x = (const float*)d_in[0];
    const float* W = (const float*)d_in[1];
    const float* b = (const float*)d_in[2];
    float* out = (float*)d_out;

    // mask region is scatter-written: zero it first (d_out is poisoned 0xAA)
    hipMemsetAsync(out + OFF_MASK, 0, (size_t)MASK_ELEMS * sizeof(float), stream);

    hipLaunchKernelGGL(router_gemm, dim3(N_TOK / 64), dim3(256), 0, stream,
                       x, W, b, out + OFF_ROUTER);
    hipLaunchKernelGGL(router_topk, dim3(N_TOK / 4), dim3(256), 0, stream,
                       out + OFF_ROUTER, out);
}

// Round 2
// 455.351 us; speedup vs baseline: 4.2492x; 4.2492x over previous
//
#include <hip/hip_runtime.h>

#define N_TOK 16384
#define HID   4096
#define N_EXP 64
#define TOPK  8

#define SPLIT  4
#define KSLICE (HID / SPLIT)   // 1024
#define CH     32              // h-chunk per stage
#define NCH    (KSLICE / CH)   // 32
#define LSTR   68              // LDS row stride (floats): 16B-aligned quads, conflict-free

// d_out layout (floats, concatenated in reference return order)
#define OFF_WT   (N_TOK * N_EXP)
#define OFF_IDX  (OFF_WT + N_TOK * TOPK)
#define OFF_MASK (OFF_IDX + N_TOK * TOPK)

// ---------------------------------------------------------------------------
// Kernel A: split-K register-tiled fp32 GEMM. router += x @ W^T (partial).
// Grid = 256 token-blocks x SPLIT k-slices. Block tile 64 tok x 64 exp.
// Thread tile 4x4; operands via broadcast-heavy ds_read_b128 (free per m136).
// ---------------------------------------------------------------------------
__global__ __launch_bounds__(256, 4)
void router_gemm(const float* __restrict__ x, const float* __restrict__ W,
                 float* __restrict__ router)
{
    __shared__ float xs[2][CH][LSTR];
    __shared__ float ws[2][CH][LSTR];

    const int tid = threadIdx.x;
    const int tb  = blockIdx.x & 255;    // token block
    const int ks  = blockIdx.x >> 8;     // k slice
    const long t0 = (long)tb * 64;
    const int h0  = ks * KSLICE;

    // compute-role indices
    const int lane = tid & 63;
    const int wv   = tid >> 6;
    const int eg   = lane & 15;          // expert quad 0..15
    const int tg   = lane >> 4;          // token quad 0..3
    const int trow = wv * 16 + tg * 4;   // token offset in tile (0..60)
    const int ecol = eg * 4;             // expert offset (0..60)

    // staging-role indices: float4 f = tid (+256); row tf = f>>3, hquad = f&7
    const int tf = tid >> 3;             // 0..31 (and +32)
    const int hq = tid & 7;

    const float* xsrc = x + (t0 + tf) * (long)HID + h0 + 4 * hq;
    const float* wsrc = W + (long)tf * HID + h0 + 4 * hq;

    float acc[4][4] = {{0.f}};

    // prefetch chunk 0
    float4 px0 = *(const float4*)(xsrc);
    float4 px1 = *(const float4*)(xsrc + 32 * (long)HID);
    float4 pw0 = *(const float4*)(wsrc);
    float4 pw1 = *(const float4*)(wsrc + 32 * (long)HID);

#pragma unroll
    for (int j = 0; j < 4; ++j) {
        xs[0][4 * hq + j][tf]      = ((const float*)&px0)[j];
        xs[0][4 * hq + j][tf + 32] = ((const float*)&px1)[j];
        ws[0][4 * hq + j][tf]      = ((const float*)&pw0)[j];
        ws[0][4 * hq + j][tf + 32] = ((const float*)&pw1)[j];
    }
    __syncthreads();

    for (int c = 0; c < NCH; ++c) {
        const int buf = c & 1;

        if (c + 1 < NCH) {   // register prefetch of next chunk
            const float* xn = xsrc + (c + 1) * CH;
            const float* wn = wsrc + (c + 1) * CH;
            px0 = *(const float4*)(xn);
            px1 = *(const float4*)(xn + 32 * (long)HID);
            pw0 = *(const float4*)(wn);
            pw1 = *(const float4*)(wn + 32 * (long)HID);
        }

#pragma unroll 4
        for (int k = 0; k < CH; ++k) {
            float4 xq = *(const float4*)&xs[buf][k][trow];
            float4 wq = *(const float4*)&ws[buf][k][ecol];
            acc[0][0] = fmaf(xq.x, wq.x, acc[0][0]);
            acc[0][1] = fmaf(xq.x, wq.y, acc[0][1]);
            acc[0][2] = fmaf(xq.x, wq.z, acc[0][2]);
            acc[0][3] = fmaf(xq.x, wq.w, acc[0][3]);
            acc[1][0] = fmaf(xq.y, wq.x, acc[1][0]);
            acc[1][1] = fmaf(xq.y, wq.y, acc[1][1]);
            acc[1][2] = fmaf(xq.y, wq.z, acc[1][2]);
            acc[1][3] = fmaf(xq.y, wq.w, acc[1][3]);
            acc[2][0] = fmaf(xq.z, wq.x, acc[2][0]);
            acc[2][1] = fmaf(xq.z, wq.y, acc[2][1]);
            acc[2][2] = fmaf(xq.z, wq.z, acc[2][2]);
            acc[2][3] = fmaf(xq.z, wq.w, acc[2][3]);
            acc[3][0] = fmaf(xq.w, wq.x, acc[3][0]);
            acc[3][1] = fmaf(xq.w, wq.y, acc[3][1]);
            acc[3][2] = fmaf(xq.w, wq.z, acc[3][2]);
            acc[3][3] = fmaf(xq.w, wq.w, acc[3][3]);
        }

        if (c + 1 < NCH) {   // write prefetched chunk into the other buffer
            const int nb = buf ^ 1;
#pragma unroll
            for (int j = 0; j < 4; ++j) {
                xs[nb][4 * hq + j][tf]      = ((const float*)&px0)[j];
                xs[nb][4 * hq + j][tf + 32] = ((const float*)&px1)[j];
                ws[nb][4 * hq + j][tf]      = ((const float*)&pw0)[j];
                ws[nb][4 * hq + j][tf + 32] = ((const float*)&pw1)[j];
            }
        }
        __syncthreads();
    }

    // epilogue: accumulate partial tile into router via HW fp32 atomics
    float* rbase = router + (t0 + trow) * (long)N_EXP + ecol;
#pragma unroll
    for (int i = 0; i < 4; ++i)
#pragma unroll
        for (int j = 0; j < 4; ++j)
            unsafeAtomicAdd(rbase + (long)i * N_EXP + j, acc[i][j]);
}

// ---------------------------------------------------------------------------
// Kernel B: add bias, rewrite router logits, softmax + top-8 (tie -> lowest
// index) + renormalized weights + scatter into one-hot mask. Wave per token.
// ---------------------------------------------------------------------------
__global__ __launch_bounds__(256)
void router_topk(float* __restrict__ router, const float* __restrict__ b,
                 float* __restrict__ out)
{
    const int tid  = threadIdx.x;
    const int lane = tid & 63;
    const int wv   = tid >> 6;
    const int n    = blockIdx.x * 4 + wv;

    float l = router[(long)n * N_EXP + lane] + b[lane];
    router[(long)n * N_EXP + lane] = l;   // restore full logit output

    // softmax over 64 experts (one logit per lane)
    float m = l;
#pragma unroll
    for (int o = 32; o > 0; o >>= 1) m = fmaxf(m, __shfl_xor(m, o));
    float p = expf(l - m);
    float Z = p;
#pragma unroll
    for (int o = 32; o > 0; o >>= 1) Z += __shfl_xor(Z, o);
    float prob = p / Z;

    // iterative top-8 via butterfly argmax (lexicographic: max val, min idx)
    float cur = prob;
    float myv = 0.f;
    int   myi = 0;
    float ssum = 0.f;
#pragma unroll
    for (int k = 0; k < TOPK; ++k) {
        float v = cur;
        int   id = lane;
#pragma unroll
        for (int o = 32; o > 0; o >>= 1) {
            float ov = __shfl_xor(v, o);
            int   oi = __shfl_xor(id, o);
            if (ov > v || (ov == v && oi < id)) { v = ov; id = oi; }
        }
        if (lane == k)  { myv = v; myi = id; }
        if (lane == id) cur = -1.f;
        ssum += v;
    }

    if (lane < TOPK) {
        out[OFF_WT  + (long)n * TOPK + lane] = myv / ssum;
        out[OFF_IDX + (long)n * TOPK + lane] = (float)myi;
        out[OFF_MASK + (long)myi * (TOPK * N_TOK) + (long)lane * N_TOK + n] = 1.0f;
    }
}

extern "C" void kernel_launch(void* const* d_in, const int* in_sizes, int n_in,
                              void* d_out, int out_size, void* d_ws, size_t ws_size,
                              hipStream_t stream)
{
    const float* x = (const float*)d_in[0];
    const float* W = (const float*)d_in[1];
    const float* b = (const float*)d_in[2];
    float* out = (float*)d_out;

    // zero everything: router region (atomic accumulation target) + mask
    hipMemsetAsync(out, 0, (size_t)out_size * sizeof(float), stream);

    hipLaunchKernelGGL(router_gemm, dim3(256 * SPLIT), dim3(256), 0, stream,
                       x, W, out);
    hipLaunchKernelGGL(router_topk, dim3(N_TOK / 4), dim3(256), 0, stream,
                       out, b, out);
}